// Round 5
// baseline (7890.098 us; speedup 1.0000x reference)
//
#include <hip/hip_runtime.h>

// LiftSplatBEV: B=2, N=6, C=64, HF=112, WF=200, D=64, BEV 200x200
#define BB   2
#define NN   6
#define CCH  64
#define HFE  112
#define WFE  200
#define DDE  64
#define HWF  (HFE*WFE)      // 22400 feature pixels (= 350*64)
#define BEVH 200
#define BEVW 200
#define HWB  (BEVH*BEVW)    // 40000 BEV cells
#define NBINS (BB*HWB)      // 80000 (b,cell) bins
#define NBINS_PAD 81920     // 320*256
#define NSCANB (NBINS_PAD/256)  // 320
#define MAXENT (BB*NN*HWF*4)    // 1,075,200 max entries
#define ACC_ELEMS ((size_t)BB*HWB*CCH)   // channel-last [b][cell][c]

// ---------------- shared geometry (bug-faithful to reference) ----------------
struct Geo {
    int valid;
    int c00, c10, c01, c11;      // cell ids in [0, HWB)
    float w00, w10, w01, w11;    // geometric bilinear weights (pre-conf)
};

__device__ __forceinline__ Geo geo_compute(int bn, int p,
    const float* __restrict__ I_inv, const float* __restrict__ E_inv,
    const float* __restrict__ Vm)
{
    Geo g; g.valid = 0;
    // bug-faithful w-outer flatten: u = p/112, v = p%112
    const float u = (float)(p / HFE);
    const float v = (float)(p % HFE);
    const float* Ii = I_inv + bn * 9;
    const float* Ei = E_inv + bn * 16;
    float cx = Ii[0]*u + Ii[1]*v + Ii[2];
    float cy = Ii[3]*u + Ii[4]*v + Ii[5];
    float cz = Ii[6]*u + Ii[7]*v + Ii[8];
    float tx = Ei[3], ty = Ei[7], tz = Ei[11];
    float dx = Ei[0]*cx + Ei[1]*cy + Ei[2] *cz + tx;   // includes translation (bug-faithful)
    float dy = Ei[4]*cx + Ei[5]*cy + Ei[6] *cz + ty;
    float dz = Ei[8]*cx + Ei[9]*cy + Ei[10]*cz + tz;
    float s  = -tz / fmaxf(dz, 1e-6f);
    float ex = tx + dx * s;
    float ey = ty + dy * s;
    float prx = Vm[0]*ex + Vm[1]*ey + Vm[2];
    float pry = Vm[3]*ex + Vm[4]*ey + Vm[5];
    float prz = Vm[6]*ex + Vm[7]*ey + Vm[8];
    float den = fmaxf(prz, 1e-7f);
    float bx = prx / den, by = pry / den;
    // bug-faithful gx->px roundtrip, same association order as reference
    float gx = bx / (float)(BEVW-1) * 2.0f - 1.0f;
    float gy = by / (float)(BEVH-1) * 2.0f - 1.0f;
    float px = (gx + 1.0f) * (float)(BEVW-1) / 2.0f;
    float py = (gy + 1.0f) * (float)(BEVH-1) / 2.0f;
    float x0f = fminf(fmaxf(floorf(px), 0.0f), (float)(BEVW-1));
    float y0f = fminf(fmaxf(floorf(py), 0.0f), (float)(BEVH-1));
    float x1f = fminf(x0f + 1.0f, (float)(BEVW-1));
    float y1f = fminf(y0f + 1.0f, (float)(BEVH-1));
    // far-edge-degenerate slots cancel exactly in the fp64 np reference: skip
    if (x0f == x1f || y0f == y1f) return g;
    float wx0 = x1f - px, wx1 = px - x0f;
    float wy0 = y1f - py, wy1 = py - y0f;
    int x0 = (int)x0f, x1 = (int)x1f, y0 = (int)y0f, y1 = (int)y1f;
    g.c00 = y0*BEVW + x0;  g.w00 = wx0*wy0;
    g.c10 = y0*BEVW + x1;  g.w10 = wx1*wy0;
    g.c01 = y1*BEVW + x0;  g.w01 = wx0*wy1;
    g.c11 = y1*BEVW + x1;  g.w11 = wx1*wy1;
    g.valid = 1;
    return g;
}

// ---------------- gather-path kernels ----------------

// A: feat [bn][c][p] -> feat_t [bn][p][c]  (both sides coalesced via LDS tile)
__global__ __launch_bounds__(256) void transpose_feat_kernel(
    const float* __restrict__ feat, float* __restrict__ feat_t)
{
    __shared__ float tile[64][65];
    const int bn = blockIdx.y, p0 = blockIdx.x * 64;
    const int lane = threadIdx.x & 63, wv = threadIdx.x >> 6;
    const float* fbase = feat + (size_t)bn * CCH * HWF + p0;
#pragma unroll
    for (int c = wv; c < CCH; c += 4)
        tile[lane][c] = fbase[(size_t)c * HWF + lane];
    __syncthreads();
    float* obase = feat_t + ((size_t)bn * HWF + p0) * CCH;
#pragma unroll
    for (int s = wv; s < 64; s += 4)
        obase[(size_t)s * CCH + lane] = tile[s][lane];
}

// C: histogram of entries per (b,cell) bin
__global__ __launch_bounds__(256) void count_kernel(
    const float* __restrict__ I_inv, const float* __restrict__ E_inv,
    const float* __restrict__ Vm, int* __restrict__ counts)
{
    const int bn = blockIdx.y;
    const int p  = blockIdx.x * blockDim.x + threadIdx.x;
    if (p >= HWF) return;
    Geo g = geo_compute(bn, p, I_inv, E_inv, Vm);
    if (!g.valid) return;
    const int base = (bn / NN) * HWB;
    atomicAdd(&counts[base + g.c00], 1);
    atomicAdd(&counts[base + g.c10], 1);
    atomicAdd(&counts[base + g.c01], 1);
    atomicAdd(&counts[base + g.c11], 1);
}

// D1: per-256-block exclusive scan of counts
__global__ __launch_bounds__(256) void scan1_kernel(
    const int* __restrict__ counts, int* __restrict__ offsets, int* __restrict__ bsum)
{
    __shared__ int tmp[256];
    const int t = threadIdx.x;
    const int i = blockIdx.x * 256 + t;
    int v = counts[i];
    tmp[t] = v; __syncthreads();
    for (int off = 1; off < 256; off <<= 1) {
        int x = (t >= off) ? tmp[t - off] : 0;
        __syncthreads();
        tmp[t] += x;
        __syncthreads();
    }
    offsets[i] = tmp[t] - v;                 // exclusive within block
    if (t == 255) bsum[blockIdx.x] = tmp[255];
}

// D2: scan the 320 block sums (single wave)
__global__ __launch_bounds__(64) void scan2_kernel(
    const int* __restrict__ bsum, int* __restrict__ bbase)
{
    const int lane = threadIdx.x;
    int carry = 0;
#pragma unroll
    for (int k = 0; k < NSCANB / 64; ++k) {
        int v = bsum[k * 64 + lane];
        int s = v;
#pragma unroll
        for (int off = 1; off < 64; off <<= 1) {
            int n = __shfl_up(s, off);
            if (lane >= off) s += n;
        }
        bbase[k * 64 + lane] = s - v + carry;
        carry += __shfl(s, 63);
    }
}

// D3: finalize offsets; init cursor
__global__ __launch_bounds__(256) void scan3_kernel(
    int* __restrict__ offsets, const int* __restrict__ bbase, int* __restrict__ cursor)
{
    const int i = blockIdx.x * 256 + threadIdx.x;
    int v = offsets[i] + bbase[blockIdx.x];
    offsets[i] = v;
    cursor[i]  = v;
}

// E: place entries (slot id + weight*conf) into bins via atomic cursor
__global__ __launch_bounds__(256) void place_kernel(
    const float* __restrict__ depth,
    const float* __restrict__ I_inv, const float* __restrict__ E_inv,
    const float* __restrict__ Vm,
    int* __restrict__ cursor, uint2* __restrict__ entries)
{
    const int bn = blockIdx.y;
    const int p  = blockIdx.x * blockDim.x + threadIdx.x;
    if (p >= HWF) return;
    Geo g = geo_compute(bn, p, I_inv, E_inv, Vm);
    if (!g.valid) return;

    // conf = max over D of depth_prob[bn,:,p] (coalesced along p per plane)
    const float* dp = depth + (size_t)bn * DDE * HWF + p;
    float conf = dp[0];
#pragma unroll 8
    for (int d = 1; d < DDE; ++d)
        conf = fmaxf(conf, dp[(size_t)d * HWF]);

    const int base = (bn / NN) * HWB;
    const unsigned bnp = (unsigned)(bn * HWF + p);
    int pos;
    pos = atomicAdd(&cursor[base + g.c00], 1);
    entries[pos] = make_uint2(bnp, __float_as_uint(g.w00 * conf));
    pos = atomicAdd(&cursor[base + g.c10], 1);
    entries[pos] = make_uint2(bnp, __float_as_uint(g.w10 * conf));
    pos = atomicAdd(&cursor[base + g.c01], 1);
    entries[pos] = make_uint2(bnp, __float_as_uint(g.w01 * conf));
    pos = atomicAdd(&cursor[base + g.c11], 1);
    entries[pos] = make_uint2(bnp, __float_as_uint(g.w11 * conf));
}

// F: per-bin gather. Block = 4 waves share one bin; lane = channel.
__global__ __launch_bounds__(256) void gather_kernel(
    const uint2* __restrict__ entries, const int* __restrict__ offsets,
    const float* __restrict__ feat_t, float* __restrict__ acc)
{
    __shared__ float sred[4][64];
    const int bin  = blockIdx.x;
    const int lane = threadIdx.x & 63, wv = threadIdx.x >> 6;
    const int start = offsets[bin], end = offsets[bin + 1];
    float a = 0.0f;
    for (int base = start + wv * 64; base < end; base += 256) {
        const int m = min(64, end - base);
        uint2 e = make_uint2(0u, 0u);
        if (lane < m) e = entries[base + lane];
        for (int j = 0; j < m; ++j) {
            int bnp = __shfl((int)e.x, j);
            int wcu = __shfl((int)e.y, j);
            float f = feat_t[(size_t)bnp * CCH + lane];   // coalesced 256B
            a = fmaf(f, __int_as_float(wcu), a);
        }
    }
    sred[wv][lane] = a;
    __syncthreads();
    if (wv == 0) {
        a += sred[1][lane] + sred[2][lane] + sred[3][lane];
        acc[(size_t)bin * CCH + lane] = a;   // plain store, single writer
    }
}

// G: out[b][c][cell] = acc[b][cell][c] / 6 (LDS transpose, both sides coalesced)
__global__ __launch_bounds__(256) void finalize_kernel(
    const float* __restrict__ acc, float* __restrict__ out)
{
    __shared__ float t[64][65];
    const int b     = blockIdx.y;
    const int cell0 = blockIdx.x * 64;
    const int lane  = threadIdx.x & 63;
    const int r     = threadIdx.x >> 6;
    const float* abase = acc + ((size_t)b * HWB + cell0) * CCH;
#pragma unroll
    for (int cell = r; cell < 64; cell += 4)
        t[cell][lane] = abase[(size_t)cell * CCH + lane];
    __syncthreads();
    float* obase = out + (size_t)b * CCH * HWB + cell0;
#pragma unroll
    for (int c = r; c < 64; c += 4)
        obase[(size_t)c * HWB + lane] = t[lane][c] * (1.0f / 6.0f);
}

// ---------------- fallback (round-4 atomic splat) if ws too small ----------------
__global__ __launch_bounds__(256) void splat_kernel(
    const float* __restrict__ feat, const float* __restrict__ depth,
    const float* __restrict__ I_inv, const float* __restrict__ E_inv,
    const float* __restrict__ Vm, float* __restrict__ acc)
{
    __shared__ float fshare[64][65];
    __shared__ float cpart[4][64];
    const int bn = blockIdx.y, b = bn / NN, p0 = blockIdx.x * 64;
    const int lane = threadIdx.x & 63, wv = threadIdx.x >> 6;
    const float* fbase = feat + (size_t)bn * CCH * HWF + p0;
#pragma unroll
    for (int c = wv; c < CCH; c += 4)
        fshare[lane][c] = fbase[(size_t)c * HWF + lane];
    const float* dbase = depth + (size_t)bn * DDE * HWF + p0;
    float m = dbase[(size_t)(wv * 16) * HWF + lane];
#pragma unroll
    for (int d = wv * 16 + 1; d < wv * 16 + 16; ++d)
        m = fmaxf(m, dbase[(size_t)d * HWF + lane]);
    cpart[wv][lane] = m;
    __syncthreads();
    float* ab = acc + ((size_t)b * HWB) * CCH + lane;
    for (int s = wv * 16; s < wv * 16 + 16; ++s) {
        Geo g = geo_compute(bn, p0 + s, I_inv, E_inv, Vm);
        if (!g.valid) continue;
        float cf = fmaxf(fmaxf(cpart[0][s], cpart[1][s]), fmaxf(cpart[2][s], cpart[3][s]));
        float f = fshare[s][lane];
        atomicAdd(ab + (size_t)g.c00 * CCH, f * (g.w00 * cf));
        atomicAdd(ab + (size_t)g.c10 * CCH, f * (g.w10 * cf));
        atomicAdd(ab + (size_t)g.c01 * CCH, f * (g.w01 * cf));
        atomicAdd(ab + (size_t)g.c11 * CCH, f * (g.w11 * cf));
    }
}

extern "C" void kernel_launch(void* const* d_in, const int* in_sizes, int n_in,
                              void* d_out, int out_size, void* d_ws, size_t ws_size,
                              hipStream_t stream) {
    const float* feat  = (const float*)d_in[0];
    const float* depth = (const float*)d_in[1];
    const float* I_inv = (const float*)d_in[2];
    const float* E_inv = (const float*)d_in[3];
    const float* Vm    = (const float*)d_in[4];
    float* out = (float*)d_out;

    // carve workspace
    size_t off = 0;
    char* wsb = (char*)d_ws;
    auto carve = [&](size_t bytes) -> void* {
        void* p = wsb + off; off += (bytes + 255) & ~(size_t)255; return p;
    };
    float* feat_t  = (float*)carve((size_t)BB * NN * CCH * HWF * 4);
    float* acc     = (float*)carve(ACC_ELEMS * 4);
    uint2* entries = (uint2*)carve((size_t)MAXENT * 8);
    int*   counts  = (int*)  carve((NBINS_PAD + 256) * 4);
    int*   offsets = (int*)  carve((NBINS_PAD + 256) * 4);
    int*   cursor  = (int*)  carve((NBINS_PAD + 256) * 4);
    int*   bsum    = (int*)  carve(NSCANB * 4);
    int*   bbase   = (int*)  carve(NSCANB * 4);

    if (off <= ws_size) {
        // ---- binned-gather path (no fp32 atomics) ----
        hipMemsetAsync(counts, 0, (NBINS_PAD + 256) * 4, stream);

        dim3 tgrid(HWF / 64, BB * NN);                 // (350,12)
        transpose_feat_kernel<<<tgrid, 256, 0, stream>>>(feat, feat_t);

        dim3 ggrid((HWF + 255) / 256, BB * NN);        // (88,12)
        count_kernel<<<ggrid, 256, 0, stream>>>(I_inv, E_inv, Vm, counts);

        scan1_kernel<<<NSCANB, 256, 0, stream>>>(counts, offsets, bsum);
        scan2_kernel<<<1, 64, 0, stream>>>(bsum, bbase);
        scan3_kernel<<<NSCANB, 256, 0, stream>>>(offsets, bbase, cursor);

        place_kernel<<<ggrid, 256, 0, stream>>>(depth, I_inv, E_inv, Vm, cursor, entries);

        gather_kernel<<<NBINS, 256, 0, stream>>>(entries, offsets, feat_t, acc);

        dim3 fgrid(HWB / 64, BB);                      // (625,2)
        finalize_kernel<<<fgrid, 256, 0, stream>>>(acc, out);
    } else {
        // ---- fallback: round-4 coalesced atomic splat ----
        float* acc0 = (float*)d_ws;
        hipMemsetAsync(acc0, 0, ACC_ELEMS * 4, stream);
        dim3 grid(HWF / 64, BB * NN);
        splat_kernel<<<grid, 256, 0, stream>>>(feat, depth, I_inv, E_inv, Vm, acc0);
        dim3 fgrid(HWB / 64, BB);
        finalize_kernel<<<fgrid, 256, 0, stream>>>(acc0, out);
    }
}

// Round 6
// 370.876 us; speedup vs baseline: 21.2742x; 21.2742x over previous
//
#include <hip/hip_runtime.h>

// LiftSplatBEV: B=2, N=6, C=64, HF=112, WF=200, D=64, BEV 200x200
#define BB   2
#define NN   6
#define CCH  64
#define HFE  112
#define WFE  200
#define DDE  64
#define HWF  (HFE*WFE)      // 22400 feature pixels (= 350*64)
#define BEVH 200
#define BEVW 200
#define HWB  (BEVH*BEVW)    // 40000 BEV cells
#define NBINS (BB*HWB)      // 80000 (b,cell) bins
#define NBINS_PAD 81920     // 320*256
#define NSCANB (NBINS_PAD/256)  // 320
#define MAXENT (BB*NN*HWF*4)    // 1,075,200 max entries (4 per valid slot)
#define NCHUNK (MAXENT/64)      // 16800 64-entry chunks
#define ACC_ELEMS ((size_t)BB*HWB*CCH)   // channel-last [b*HWB+cell][c]

// ---------------- shared geometry (bug-faithful to reference) ----------------
struct Geo {
    int valid;
    int c00, c10, c01, c11;      // cell ids in [0, HWB)
    float w00, w10, w01, w11;    // geometric bilinear weights (pre-conf)
};

__device__ __forceinline__ Geo geo_compute(int bn, int p,
    const float* __restrict__ I_inv, const float* __restrict__ E_inv,
    const float* __restrict__ Vm)
{
    Geo g; g.valid = 0;
    // bug-faithful w-outer flatten: u = p/112, v = p%112
    const float u = (float)(p / HFE);
    const float v = (float)(p % HFE);
    const float* Ii = I_inv + bn * 9;
    const float* Ei = E_inv + bn * 16;
    float cx = Ii[0]*u + Ii[1]*v + Ii[2];
    float cy = Ii[3]*u + Ii[4]*v + Ii[5];
    float cz = Ii[6]*u + Ii[7]*v + Ii[8];
    float tx = Ei[3], ty = Ei[7], tz = Ei[11];
    float dx = Ei[0]*cx + Ei[1]*cy + Ei[2] *cz + tx;   // includes translation (bug-faithful)
    float dy = Ei[4]*cx + Ei[5]*cy + Ei[6] *cz + ty;
    float dz = Ei[8]*cx + Ei[9]*cy + Ei[10]*cz + tz;
    float s  = -tz / fmaxf(dz, 1e-6f);
    float ex = tx + dx * s;
    float ey = ty + dy * s;
    float prx = Vm[0]*ex + Vm[1]*ey + Vm[2];
    float pry = Vm[3]*ex + Vm[4]*ey + Vm[5];
    float prz = Vm[6]*ex + Vm[7]*ey + Vm[8];
    float den = fmaxf(prz, 1e-7f);
    float bx = prx / den, by = pry / den;
    // bug-faithful gx->px roundtrip, same association order as reference
    float gx = bx / (float)(BEVW-1) * 2.0f - 1.0f;
    float gy = by / (float)(BEVH-1) * 2.0f - 1.0f;
    float px = (gx + 1.0f) * (float)(BEVW-1) / 2.0f;
    float py = (gy + 1.0f) * (float)(BEVH-1) / 2.0f;
    float x0f = fminf(fmaxf(floorf(px), 0.0f), (float)(BEVW-1));
    float y0f = fminf(fmaxf(floorf(py), 0.0f), (float)(BEVH-1));
    float x1f = fminf(x0f + 1.0f, (float)(BEVW-1));
    float y1f = fminf(y0f + 1.0f, (float)(BEVH-1));
    // far-edge-degenerate slots cancel exactly in the fp64 np reference: skip
    if (x0f == x1f || y0f == y1f) return g;
    float wx0 = x1f - px, wx1 = px - x0f;
    float wy0 = y1f - py, wy1 = py - y0f;
    int x0 = (int)x0f, x1 = (int)x1f, y0 = (int)y0f, y1 = (int)y1f;
    g.c00 = y0*BEVW + x0;  g.w00 = wx0*wy0;
    g.c10 = y0*BEVW + x1;  g.w10 = wx1*wy0;
    g.c01 = y1*BEVW + x0;  g.w01 = wx0*wy1;
    g.c11 = y1*BEVW + x1;  g.w11 = wx1*wy1;
    g.valid = 1;
    return g;
}

// Wave-run aggregation: consecutive lanes holding the same cell form a run.
// Returns leader flag, run length (valid at leader), and my leader's lane.
__device__ __forceinline__ void run_info(int cell, int lane,
                                         bool& leader, int& runlen, int& leadlane)
{
    int prev = __shfl_up(cell, 1);
    bool change = (lane == 0) || (cell != prev);
    unsigned long long bal = __ballot(change);
    unsigned long long below = bal & (~0ull >> (63 - lane));   // change bits at [0..lane]
    leadlane = 63 - __builtin_clzll(below);                    // bit0 always set
    unsigned long long above = (lane == 63) ? 0ull : (bal >> (lane + 1));
    int next = (above == 0ull) ? 64 : (lane + 1 + __builtin_ffsll((long long)above) - 1);
    runlen = next - lane;
    leader = change && (cell >= 0);
}

// ---------------- gather-path kernels ----------------

// A: feat [bn][c][p] -> feat_t [bn][p][c]  (both sides coalesced via LDS tile)
__global__ __launch_bounds__(256) void transpose_feat_kernel(
    const float* __restrict__ feat, float* __restrict__ feat_t)
{
    __shared__ float tile[64][65];
    const int bn = blockIdx.y, p0 = blockIdx.x * 64;
    const int lane = threadIdx.x & 63, wv = threadIdx.x >> 6;
    const float* fbase = feat + (size_t)bn * CCH * HWF + p0;
#pragma unroll
    for (int c = wv; c < CCH; c += 4)
        tile[lane][c] = fbase[(size_t)c * HWF + lane];
    __syncthreads();
    float* obase = feat_t + ((size_t)bn * HWF + p0) * CCH;
#pragma unroll
    for (int s = wv; s < 64; s += 4)
        obase[(size_t)s * CCH + lane] = tile[s][lane];
}

// C: histogram of entries per (b,cell) bin, run-aggregated atomics
__global__ __launch_bounds__(256) void count_kernel(
    const float* __restrict__ I_inv, const float* __restrict__ E_inv,
    const float* __restrict__ Vm, int* __restrict__ counts)
{
    const int bn = blockIdx.y;
    const int p  = blockIdx.x * blockDim.x + threadIdx.x;
    const int lane = threadIdx.x & 63;
    const int inb = (p < HWF);
    Geo g = geo_compute(bn, inb ? p : HWF - 1, I_inv, E_inv, Vm);
    const int valid = inb && g.valid;
    const int base = (bn / NN) * HWB;
    const int cells[4] = { valid ? base + g.c00 : -1, valid ? base + g.c10 : -1,
                           valid ? base + g.c01 : -1, valid ? base + g.c11 : -1 };
#pragma unroll
    for (int k = 0; k < 4; ++k) {
        bool leader; int runlen, leadlane;
        run_info(cells[k], lane, leader, runlen, leadlane);
        if (leader) atomicAdd(&counts[cells[k]], runlen);
    }
}

// D1: per-256-block exclusive scan of counts
__global__ __launch_bounds__(256) void scan1_kernel(
    const int* __restrict__ counts, int* __restrict__ offsets, int* __restrict__ bsum)
{
    __shared__ int tmp[256];
    const int t = threadIdx.x;
    const int i = blockIdx.x * 256 + t;
    int v = counts[i];
    tmp[t] = v; __syncthreads();
    for (int off = 1; off < 256; off <<= 1) {
        int x = (t >= off) ? tmp[t - off] : 0;
        __syncthreads();
        tmp[t] += x;
        __syncthreads();
    }
    offsets[i] = tmp[t] - v;
    if (t == 255) bsum[blockIdx.x] = tmp[255];
}

// D2: scan the 320 block sums (single wave)
__global__ __launch_bounds__(64) void scan2_kernel(
    const int* __restrict__ bsum, int* __restrict__ bbase)
{
    const int lane = threadIdx.x;
    int carry = 0;
#pragma unroll
    for (int k = 0; k < NSCANB / 64; ++k) {
        int v = bsum[k * 64 + lane];
        int s = v;
#pragma unroll
        for (int off = 1; off < 64; off <<= 1) {
            int n = __shfl_up(s, off);
            if (lane >= off) s += n;
        }
        bbase[k * 64 + lane] = s - v + carry;
        carry += __shfl(s, 63);
    }
}

// D3: finalize offsets; init cursor
__global__ __launch_bounds__(256) void scan3_kernel(
    int* __restrict__ offsets, const int* __restrict__ bbase, int* __restrict__ cursor)
{
    const int i = blockIdx.x * 256 + threadIdx.x;
    int v = offsets[i] + bbase[blockIdx.x];
    offsets[i] = v;
    cursor[i]  = v;
}

// E: place entries, run-aggregated cursor atomics + contiguous run writes
__global__ __launch_bounds__(256) void place_kernel(
    const float* __restrict__ depth,
    const float* __restrict__ I_inv, const float* __restrict__ E_inv,
    const float* __restrict__ Vm,
    int* __restrict__ cursor, int* __restrict__ ebin, uint2* __restrict__ entries)
{
    const int bn = blockIdx.y;
    const int p  = blockIdx.x * blockDim.x + threadIdx.x;
    const int lane = threadIdx.x & 63;
    const int inb = (p < HWF);
    const int pp = inb ? p : HWF - 1;
    Geo g = geo_compute(bn, pp, I_inv, E_inv, Vm);
    const int valid = inb && g.valid;
    const int base = (bn / NN) * HWB;

    // conf = max over D of depth_prob[bn,:,p] (coalesced along p per plane)
    const float* dpb = depth + (size_t)bn * DDE * HWF + pp;
    float conf = dpb[0];
#pragma unroll 8
    for (int d = 1; d < DDE; ++d)
        conf = fmaxf(conf, dpb[(size_t)d * HWF]);

    const unsigned bnp = (unsigned)(bn * HWF + pp);
    const int   cells[4] = { valid ? base + g.c00 : -1, valid ? base + g.c10 : -1,
                             valid ? base + g.c01 : -1, valid ? base + g.c11 : -1 };
    const float ws[4] = { g.w00 * conf, g.w10 * conf, g.w01 * conf, g.w11 * conf };

#pragma unroll
    for (int k = 0; k < 4; ++k) {
        bool leader; int runlen, leadlane;
        run_info(cells[k], lane, leader, runlen, leadlane);
        int pos_leader = 0;
        if (leader) pos_leader = atomicAdd(&cursor[cells[k]], runlen);
        int pos = __shfl(pos_leader, leadlane) + (lane - leadlane);
        if (valid) {
            ebin[pos]    = cells[k];
            entries[pos] = make_uint2(bnp, __float_as_uint(ws[k]));
        }
    }
}

// F: segmented gather. One wave per 64-entry chunk; lane = channel.
// total % 4 == 0 (4 entries per valid slot), so the 4-unrolled walk needs no
// per-entry guards; flush acc[bin][lane] on bin transitions (wave-uniform).
__global__ __launch_bounds__(256) void gather_seg_kernel(
    const int* __restrict__ ebin, const uint2* __restrict__ entries,
    const int* __restrict__ total_ptr,
    const float* __restrict__ feat_t, float* __restrict__ acc)
{
    const int lane = threadIdx.x & 63, wv = threadIdx.x >> 6;
    const int chunk = blockIdx.x * 4 + wv;
    const int total = *total_ptr;
    const int start = chunk * 64;
    if (start >= total) return;
    const int m = min(64, total - start);   // multiple of 4

    int myb = -1;
    uint2 mye = make_uint2(0u, 0u);
    if (lane < m) { myb = ebin[start + lane]; mye = entries[start + lane]; }

    float a = 0.0f;
    for (int j = 0; j < m; j += 4) {
        int b0 = __shfl(myb, j + 0), b1 = __shfl(myb, j + 1);
        int b2 = __shfl(myb, j + 2), b3 = __shfl(myb, j + 3);
        int b4 = (j + 4 < 64) ? __shfl(myb, j + 4) : -2;   // lanes >= m hold -1 -> flush
        unsigned x0 = (unsigned)__shfl((int)mye.x, j + 0), w0 = (unsigned)__shfl((int)mye.y, j + 0);
        unsigned x1 = (unsigned)__shfl((int)mye.x, j + 1), w1 = (unsigned)__shfl((int)mye.y, j + 1);
        unsigned x2 = (unsigned)__shfl((int)mye.x, j + 2), w2 = (unsigned)__shfl((int)mye.y, j + 2);
        unsigned x3 = (unsigned)__shfl((int)mye.x, j + 3), w3 = (unsigned)__shfl((int)mye.y, j + 3);
        float f0 = feat_t[(size_t)x0 * CCH + lane];   // 4 independent coalesced 256B loads
        float f1 = feat_t[(size_t)x1 * CCH + lane];
        float f2 = feat_t[(size_t)x2 * CCH + lane];
        float f3 = feat_t[(size_t)x3 * CCH + lane];
        a = fmaf(f0, __uint_as_float(w0), a);
        if (b0 != b1) { atomicAdd(&acc[(size_t)b0 * CCH + lane], a); a = 0.0f; }
        a = fmaf(f1, __uint_as_float(w1), a);
        if (b1 != b2) { atomicAdd(&acc[(size_t)b1 * CCH + lane], a); a = 0.0f; }
        a = fmaf(f2, __uint_as_float(w2), a);
        if (b2 != b3) { atomicAdd(&acc[(size_t)b2 * CCH + lane], a); a = 0.0f; }
        a = fmaf(f3, __uint_as_float(w3), a);
        if (b3 != b4) { atomicAdd(&acc[(size_t)b3 * CCH + lane], a); a = 0.0f; }
    }
}

// G: out[b][c][cell] = acc[b*HWB+cell][c] / 6 (LDS transpose, both sides coalesced)
__global__ __launch_bounds__(256) void finalize_kernel(
    const float* __restrict__ acc, float* __restrict__ out)
{
    __shared__ float t[64][65];
    const int b     = blockIdx.y;
    const int cell0 = blockIdx.x * 64;
    const int lane  = threadIdx.x & 63;
    const int r     = threadIdx.x >> 6;
    const float* abase = acc + ((size_t)b * HWB + cell0) * CCH;
#pragma unroll
    for (int cell = r; cell < 64; cell += 4)
        t[cell][lane] = abase[(size_t)cell * CCH + lane];
    __syncthreads();
    float* obase = out + (size_t)b * CCH * HWB + cell0;
#pragma unroll
    for (int c = r; c < 64; c += 4)
        obase[(size_t)c * HWB + lane] = t[lane][c] * (1.0f / 6.0f);
}

// ---------------- fallback (round-4 atomic splat) if ws too small ----------------
__global__ __launch_bounds__(256) void splat_kernel(
    const float* __restrict__ feat, const float* __restrict__ depth,
    const float* __restrict__ I_inv, const float* __restrict__ E_inv,
    const float* __restrict__ Vm, float* __restrict__ acc)
{
    __shared__ float fshare[64][65];
    __shared__ float cpart[4][64];
    const int bn = blockIdx.y, b = bn / NN, p0 = blockIdx.x * 64;
    const int lane = threadIdx.x & 63, wv = threadIdx.x >> 6;
    const float* fbase = feat + (size_t)bn * CCH * HWF + p0;
#pragma unroll
    for (int c = wv; c < CCH; c += 4)
        fshare[lane][c] = fbase[(size_t)c * HWF + lane];
    const float* dbase = depth + (size_t)bn * DDE * HWF + p0;
    float m = dbase[(size_t)(wv * 16) * HWF + lane];
#pragma unroll
    for (int d = wv * 16 + 1; d < wv * 16 + 16; ++d)
        m = fmaxf(m, dbase[(size_t)d * HWF + lane]);
    cpart[wv][lane] = m;
    __syncthreads();
    float* ab = acc + ((size_t)b * HWB) * CCH + lane;
    for (int s = wv * 16; s < wv * 16 + 16; ++s) {
        Geo g = geo_compute(bn, p0 + s, I_inv, E_inv, Vm);
        if (!g.valid) continue;
        float cf = fmaxf(fmaxf(cpart[0][s], cpart[1][s]), fmaxf(cpart[2][s], cpart[3][s]));
        float f = fshare[s][lane];
        atomicAdd(ab + (size_t)g.c00 * CCH, f * (g.w00 * cf));
        atomicAdd(ab + (size_t)g.c10 * CCH, f * (g.w10 * cf));
        atomicAdd(ab + (size_t)g.c01 * CCH, f * (g.w01 * cf));
        atomicAdd(ab + (size_t)g.c11 * CCH, f * (g.w11 * cf));
    }
}

extern "C" void kernel_launch(void* const* d_in, const int* in_sizes, int n_in,
                              void* d_out, int out_size, void* d_ws, size_t ws_size,
                              hipStream_t stream) {
    const float* feat  = (const float*)d_in[0];
    const float* depth = (const float*)d_in[1];
    const float* I_inv = (const float*)d_in[2];
    const float* E_inv = (const float*)d_in[3];
    const float* Vm    = (const float*)d_in[4];
    float* out = (float*)d_out;

    size_t off = 0;
    char* wsb = (char*)d_ws;
    auto carve = [&](size_t bytes) -> void* {
        void* p = wsb + off; off += (bytes + 255) & ~(size_t)255; return p;
    };
    float* feat_t  = (float*)carve((size_t)BB * NN * CCH * HWF * 4);  // 68.8 MB
    float* acc     = (float*)carve(ACC_ELEMS * 4);                    // 20.5 MB
    uint2* entries = (uint2*)carve((size_t)MAXENT * 8);               //  8.6 MB
    int*   ebin    = (int*)  carve((size_t)MAXENT * 4);               //  4.3 MB
    int*   counts  = (int*)  carve((NBINS_PAD + 256) * 4);
    int*   offsets = (int*)  carve((NBINS_PAD + 256) * 4);
    int*   cursor  = (int*)  carve((NBINS_PAD + 256) * 4);
    int*   bsum    = (int*)  carve(NSCANB * 4);
    int*   bbase   = (int*)  carve(NSCANB * 4);

    if (off <= ws_size) {
        hipMemsetAsync(counts, 0, (NBINS_PAD + 256) * 4, stream);
        hipMemsetAsync(acc, 0, ACC_ELEMS * 4, stream);

        dim3 tgrid(HWF / 64, BB * NN);                 // (350,12)
        transpose_feat_kernel<<<tgrid, 256, 0, stream>>>(feat, feat_t);

        dim3 ggrid((HWF + 255) / 256, BB * NN);        // (88,12)
        count_kernel<<<ggrid, 256, 0, stream>>>(I_inv, E_inv, Vm, counts);

        scan1_kernel<<<NSCANB, 256, 0, stream>>>(counts, offsets, bsum);
        scan2_kernel<<<1, 64, 0, stream>>>(bsum, bbase);
        scan3_kernel<<<NSCANB, 256, 0, stream>>>(offsets, bbase, cursor);

        place_kernel<<<ggrid, 256, 0, stream>>>(depth, I_inv, E_inv, Vm,
                                                cursor, ebin, entries);

        gather_seg_kernel<<<NCHUNK / 4, 256, 0, stream>>>(
            ebin, entries, offsets + NBINS, feat_t, acc);

        dim3 fgrid(HWB / 64, BB);                      // (625,2)
        finalize_kernel<<<fgrid, 256, 0, stream>>>(acc, out);
    } else {
        float* acc0 = (float*)d_ws;
        hipMemsetAsync(acc0, 0, ACC_ELEMS * 4, stream);
        dim3 grid(HWF / 64, BB * NN);
        splat_kernel<<<grid, 256, 0, stream>>>(feat, depth, I_inv, E_inv, Vm, acc0);
        dim3 fgrid(HWB / 64, BB);
        finalize_kernel<<<fgrid, 256, 0, stream>>>(acc0, out);
    }
}

// Round 7
// 363.403 us; speedup vs baseline: 21.7117x; 1.0206x over previous
//
#include <hip/hip_runtime.h>

// LiftSplatBEV: B=2, N=6, C=64, HF=112, WF=200, D=64, BEV 200x200
#define BB   2
#define NN   6
#define CCH  64
#define HFE  112
#define WFE  200
#define DDE  64
#define HWF  (HFE*WFE)      // 22400 feature pixels (= 350*64)
#define BEVH 200
#define BEVW 200
#define HWB  (BEVH*BEVW)    // 40000 BEV cells
#define NBINS (BB*HWB)      // 80000 (b,cell) bins
#define NBINS_PAD 81920     // 320*256
#define NSCANB (NBINS_PAD/256)  // 320
#define MAXENT (BB*NN*HWF*4)    // 1,075,200 max entries (4 per valid slot)
#define NCHUNK (MAXENT/64)      // 16800 64-entry chunks
#define ACC_ELEMS ((size_t)BB*HWB*CCH)   // channel-last [b*HWB+cell][c]

// ---------------- shared geometry (bug-faithful to reference) ----------------
struct Geo {
    int valid;
    int c00, c10, c01, c11;      // cell ids in [0, HWB)
    float w00, w10, w01, w11;    // geometric bilinear weights (pre-conf)
};

__device__ __forceinline__ Geo geo_compute(int bn, int p,
    const float* __restrict__ I_inv, const float* __restrict__ E_inv,
    const float* __restrict__ Vm)
{
    Geo g; g.valid = 0;
    // bug-faithful w-outer flatten: u = p/112, v = p%112
    const float u = (float)(p / HFE);
    const float v = (float)(p % HFE);
    const float* Ii = I_inv + bn * 9;
    const float* Ei = E_inv + bn * 16;
    float cx = Ii[0]*u + Ii[1]*v + Ii[2];
    float cy = Ii[3]*u + Ii[4]*v + Ii[5];
    float cz = Ii[6]*u + Ii[7]*v + Ii[8];
    float tx = Ei[3], ty = Ei[7], tz = Ei[11];
    float dx = Ei[0]*cx + Ei[1]*cy + Ei[2] *cz + tx;   // includes translation (bug-faithful)
    float dy = Ei[4]*cx + Ei[5]*cy + Ei[6] *cz + ty;
    float dz = Ei[8]*cx + Ei[9]*cy + Ei[10]*cz + tz;
    float s  = -tz / fmaxf(dz, 1e-6f);
    float ex = tx + dx * s;
    float ey = ty + dy * s;
    float prx = Vm[0]*ex + Vm[1]*ey + Vm[2];
    float pry = Vm[3]*ex + Vm[4]*ey + Vm[5];
    float prz = Vm[6]*ex + Vm[7]*ey + Vm[8];
    float den = fmaxf(prz, 1e-7f);
    float bx = prx / den, by = pry / den;
    // bug-faithful gx->px roundtrip, same association order as reference
    float gx = bx / (float)(BEVW-1) * 2.0f - 1.0f;
    float gy = by / (float)(BEVH-1) * 2.0f - 1.0f;
    float px = (gx + 1.0f) * (float)(BEVW-1) / 2.0f;
    float py = (gy + 1.0f) * (float)(BEVH-1) / 2.0f;
    float x0f = fminf(fmaxf(floorf(px), 0.0f), (float)(BEVW-1));
    float y0f = fminf(fmaxf(floorf(py), 0.0f), (float)(BEVH-1));
    float x1f = fminf(x0f + 1.0f, (float)(BEVW-1));
    float y1f = fminf(y0f + 1.0f, (float)(BEVH-1));
    // far-edge-degenerate slots cancel exactly in the fp64 np reference: skip
    if (x0f == x1f || y0f == y1f) return g;
    float wx0 = x1f - px, wx1 = px - x0f;
    float wy0 = y1f - py, wy1 = py - y0f;
    int x0 = (int)x0f, x1 = (int)x1f, y0 = (int)y0f, y1 = (int)y1f;
    g.c00 = y0*BEVW + x0;  g.w00 = wx0*wy0;
    g.c10 = y0*BEVW + x1;  g.w10 = wx1*wy0;
    g.c01 = y1*BEVW + x0;  g.w01 = wx0*wy1;
    g.c11 = y1*BEVW + x1;  g.w11 = wx1*wy1;
    g.valid = 1;
    return g;
}

// Wave-run aggregation: consecutive lanes holding the same cell form a run.
__device__ __forceinline__ void run_info(int cell, int lane,
                                         bool& leader, int& runlen, int& leadlane)
{
    int prev = __shfl_up(cell, 1);
    bool change = (lane == 0) || (cell != prev);
    unsigned long long bal = __ballot(change);
    unsigned long long below = bal & (~0ull >> (63 - lane));   // change bits at [0..lane]
    leadlane = 63 - __builtin_clzll(below);                    // bit0 always set
    unsigned long long above = (lane == 63) ? 0ull : (bal >> (lane + 1));
    int next = (above == 0ull) ? 64 : (lane + 1 + __builtin_ffsll((long long)above) - 1);
    runlen = next - lane;
    leader = change && (cell >= 0);
}

// ---------------- fused prep: feat transpose + conf + bin histogram ----------------
// Grid (88, 12), block 256. Covers p in [p0, p0+256) of camera bn.
__global__ __launch_bounds__(256) void prep_kernel(
    const float* __restrict__ feat,    // [12,64,22400]
    const float* __restrict__ depth,   // [12,64,22400]
    const float* __restrict__ I_inv, const float* __restrict__ E_inv,
    const float* __restrict__ Vm,
    float* __restrict__ feat_t,        // [12,22400,64]
    float* __restrict__ conf,          // [12,22400]
    int* __restrict__ counts)          // [NBINS_PAD]
{
    __shared__ float tile[64][65];
    const int bn  = blockIdx.y;
    const int p0  = blockIdx.x * 256;
    const int tid = threadIdx.x, lane = tid & 63, wv = tid >> 6;

    // -- A: transpose up to 4 tiles of 64 pixels (both sides coalesced)
    const float* fcam = feat   + (size_t)bn * CCH * HWF;
    float*       ocam = feat_t + (size_t)bn * HWF * CCH;
#pragma unroll
    for (int t = 0; t < 4; ++t) {
        const int pb = p0 + t * 64;
        if (pb < HWF) {
#pragma unroll
            for (int c = wv; c < CCH; c += 4)
                tile[lane][c] = fcam[(size_t)c * HWF + pb + lane];
        }
        __syncthreads();
        if (pb < HWF) {
#pragma unroll
            for (int s = wv; s < 64; s += 4)
                ocam[(size_t)(pb + s) * CCH + lane] = tile[s][lane];
        }
        __syncthreads();
    }

    // -- B: conf[bn][p] = max_d depth[bn][d][p]; one p per thread
    const int p   = p0 + tid;
    const int inb = (p < HWF);
    if (inb) {
        const float* dp = depth + (size_t)bn * DDE * HWF + p;
        float cf = dp[0];
#pragma unroll 8
        for (int d = 1; d < DDE; ++d)
            cf = fmaxf(cf, dp[(size_t)d * HWF]);
        conf[(size_t)bn * HWF + p] = cf;
    }

    // -- C: histogram with run-aggregated atomics (all 64 lanes participate)
    Geo g = geo_compute(bn, inb ? p : HWF - 1, I_inv, E_inv, Vm);
    const int valid = inb && g.valid;
    const int base  = (bn / NN) * HWB;
    const int cells[4] = { valid ? base + g.c00 : -1, valid ? base + g.c10 : -1,
                           valid ? base + g.c01 : -1, valid ? base + g.c11 : -1 };
#pragma unroll
    for (int k = 0; k < 4; ++k) {
        bool leader; int runlen, leadlane;
        run_info(cells[k], lane, leader, runlen, leadlane);
        if (leader) atomicAdd(&counts[cells[k]], runlen);
    }
}

// D1: per-256-block exclusive scan of counts
__global__ __launch_bounds__(256) void scan1_kernel(
    const int* __restrict__ counts, int* __restrict__ offsets, int* __restrict__ bsum)
{
    __shared__ int tmp[256];
    const int t = threadIdx.x;
    const int i = blockIdx.x * 256 + t;
    int v = counts[i];
    tmp[t] = v; __syncthreads();
    for (int off = 1; off < 256; off <<= 1) {
        int x = (t >= off) ? tmp[t - off] : 0;
        __syncthreads();
        tmp[t] += x;
        __syncthreads();
    }
    offsets[i] = tmp[t] - v;
    if (t == 255) bsum[blockIdx.x] = tmp[255];
}

// D2: scan the 320 block sums (single wave)
__global__ __launch_bounds__(64) void scan2_kernel(
    const int* __restrict__ bsum, int* __restrict__ bbase)
{
    const int lane = threadIdx.x;
    int carry = 0;
#pragma unroll
    for (int k = 0; k < NSCANB / 64; ++k) {
        int v = bsum[k * 64 + lane];
        int s = v;
#pragma unroll
        for (int off = 1; off < 64; off <<= 1) {
            int n = __shfl_up(s, off);
            if (lane >= off) s += n;
        }
        bbase[k * 64 + lane] = s - v + carry;
        carry += __shfl(s, 63);
    }
}

// D3: finalize offsets; init cursor
__global__ __launch_bounds__(256) void scan3_kernel(
    int* __restrict__ offsets, const int* __restrict__ bbase, int* __restrict__ cursor)
{
    const int i = blockIdx.x * 256 + threadIdx.x;
    int v = offsets[i] + bbase[blockIdx.x];
    offsets[i] = v;
    cursor[i]  = v;
}

// E: place entries (lean: conf preloaded), run-aggregated cursor atomics
__global__ __launch_bounds__(256) void place_kernel(
    const float* __restrict__ conf,
    const float* __restrict__ I_inv, const float* __restrict__ E_inv,
    const float* __restrict__ Vm,
    int* __restrict__ cursor, int* __restrict__ ebin, uint2* __restrict__ entries)
{
    const int bn = blockIdx.y;
    const int p  = blockIdx.x * blockDim.x + threadIdx.x;
    const int lane = threadIdx.x & 63;
    const int inb = (p < HWF);
    const int pp = inb ? p : HWF - 1;
    Geo g = geo_compute(bn, pp, I_inv, E_inv, Vm);
    const int valid = inb && g.valid;
    const int base = (bn / NN) * HWB;

    const float cf = conf[(size_t)bn * HWF + pp];
    const unsigned bnp = (unsigned)(bn * HWF + pp);
    const int   cells[4] = { valid ? base + g.c00 : -1, valid ? base + g.c10 : -1,
                             valid ? base + g.c01 : -1, valid ? base + g.c11 : -1 };
    const float ws[4] = { g.w00 * cf, g.w10 * cf, g.w01 * cf, g.w11 * cf };

#pragma unroll
    for (int k = 0; k < 4; ++k) {
        bool leader; int runlen, leadlane;
        run_info(cells[k], lane, leader, runlen, leadlane);
        int pos_leader = 0;
        if (leader) pos_leader = atomicAdd(&cursor[cells[k]], runlen);
        int pos = __shfl(pos_leader, leadlane) + (lane - leadlane);
        if (valid) {
            ebin[pos]    = cells[k];
            entries[pos] = make_uint2(bnp, __float_as_uint(ws[k]));
        }
    }
}

// F: segmented gather. One wave per 64-entry chunk; lane = channel.
__global__ __launch_bounds__(256) void gather_seg_kernel(
    const int* __restrict__ ebin, const uint2* __restrict__ entries,
    const int* __restrict__ total_ptr,
    const float* __restrict__ feat_t, float* __restrict__ acc)
{
    const int lane = threadIdx.x & 63, wv = threadIdx.x >> 6;
    const int chunk = blockIdx.x * 4 + wv;
    const int total = *total_ptr;
    const int start = chunk * 64;
    if (start >= total) return;
    const int m = min(64, total - start);   // multiple of 4

    int myb = -1;
    uint2 mye = make_uint2(0u, 0u);
    if (lane < m) { myb = ebin[start + lane]; mye = entries[start + lane]; }

    float a = 0.0f;
    for (int j = 0; j < m; j += 4) {
        int b0 = __shfl(myb, j + 0), b1 = __shfl(myb, j + 1);
        int b2 = __shfl(myb, j + 2), b3 = __shfl(myb, j + 3);
        int b4 = (j + 4 < 64) ? __shfl(myb, j + 4) : -2;   // lanes >= m hold -1 -> flush
        unsigned x0 = (unsigned)__shfl((int)mye.x, j + 0), w0 = (unsigned)__shfl((int)mye.y, j + 0);
        unsigned x1 = (unsigned)__shfl((int)mye.x, j + 1), w1 = (unsigned)__shfl((int)mye.y, j + 1);
        unsigned x2 = (unsigned)__shfl((int)mye.x, j + 2), w2 = (unsigned)__shfl((int)mye.y, j + 2);
        unsigned x3 = (unsigned)__shfl((int)mye.x, j + 3), w3 = (unsigned)__shfl((int)mye.y, j + 3);
        float f0 = feat_t[(size_t)x0 * CCH + lane];   // 4 independent coalesced 256B loads
        float f1 = feat_t[(size_t)x1 * CCH + lane];
        float f2 = feat_t[(size_t)x2 * CCH + lane];
        float f3 = feat_t[(size_t)x3 * CCH + lane];
        a = fmaf(f0, __uint_as_float(w0), a);
        if (b0 != b1) { atomicAdd(&acc[(size_t)b0 * CCH + lane], a); a = 0.0f; }
        a = fmaf(f1, __uint_as_float(w1), a);
        if (b1 != b2) { atomicAdd(&acc[(size_t)b1 * CCH + lane], a); a = 0.0f; }
        a = fmaf(f2, __uint_as_float(w2), a);
        if (b2 != b3) { atomicAdd(&acc[(size_t)b2 * CCH + lane], a); a = 0.0f; }
        a = fmaf(f3, __uint_as_float(w3), a);
        if (b3 != b4) { atomicAdd(&acc[(size_t)b3 * CCH + lane], a); a = 0.0f; }
    }
}

// G: out[b][c][cell] = acc[b*HWB+cell][c] / 6 (LDS transpose, both sides coalesced)
__global__ __launch_bounds__(256) void finalize_kernel(
    const float* __restrict__ acc, float* __restrict__ out)
{
    __shared__ float t[64][65];
    const int b     = blockIdx.y;
    const int cell0 = blockIdx.x * 64;
    const int lane  = threadIdx.x & 63;
    const int r     = threadIdx.x >> 6;
    const float* abase = acc + ((size_t)b * HWB + cell0) * CCH;
#pragma unroll
    for (int cell = r; cell < 64; cell += 4)
        t[cell][lane] = abase[(size_t)cell * CCH + lane];
    __syncthreads();
    float* obase = out + (size_t)b * CCH * HWB + cell0;
#pragma unroll
    for (int c = r; c < 64; c += 4)
        obase[(size_t)c * HWB + lane] = t[lane][c] * (1.0f / 6.0f);
}

// ---------------- fallback (round-4 atomic splat) if ws too small ----------------
__global__ __launch_bounds__(256) void splat_kernel(
    const float* __restrict__ feat, const float* __restrict__ depth,
    const float* __restrict__ I_inv, const float* __restrict__ E_inv,
    const float* __restrict__ Vm, float* __restrict__ acc)
{
    __shared__ float fshare[64][65];
    __shared__ float cpart[4][64];
    const int bn = blockIdx.y, b = bn / NN, p0 = blockIdx.x * 64;
    const int lane = threadIdx.x & 63, wv = threadIdx.x >> 6;
    const float* fbase = feat + (size_t)bn * CCH * HWF + p0;
#pragma unroll
    for (int c = wv; c < CCH; c += 4)
        fshare[lane][c] = fbase[(size_t)c * HWF + lane];
    const float* dbase = depth + (size_t)bn * DDE * HWF + p0;
    float m = dbase[(size_t)(wv * 16) * HWF + lane];
#pragma unroll
    for (int d = wv * 16 + 1; d < wv * 16 + 16; ++d)
        m = fmaxf(m, dbase[(size_t)d * HWF + lane]);
    cpart[wv][lane] = m;
    __syncthreads();
    float* ab = acc + ((size_t)b * HWB) * CCH + lane;
    for (int s = wv * 16; s < wv * 16 + 16; ++s) {
        Geo g = geo_compute(bn, p0 + s, I_inv, E_inv, Vm);
        if (!g.valid) continue;
        float cf = fmaxf(fmaxf(cpart[0][s], cpart[1][s]), fmaxf(cpart[2][s], cpart[3][s]));
        float f = fshare[s][lane];
        atomicAdd(ab + (size_t)g.c00 * CCH, f * (g.w00 * cf));
        atomicAdd(ab + (size_t)g.c10 * CCH, f * (g.w10 * cf));
        atomicAdd(ab + (size_t)g.c01 * CCH, f * (g.w01 * cf));
        atomicAdd(ab + (size_t)g.c11 * CCH, f * (g.w11 * cf));
    }
}

extern "C" void kernel_launch(void* const* d_in, const int* in_sizes, int n_in,
                              void* d_out, int out_size, void* d_ws, size_t ws_size,
                              hipStream_t stream) {
    const float* feat  = (const float*)d_in[0];
    const float* depth = (const float*)d_in[1];
    const float* I_inv = (const float*)d_in[2];
    const float* E_inv = (const float*)d_in[3];
    const float* Vm    = (const float*)d_in[4];
    float* out = (float*)d_out;

    size_t off = 0;
    char* wsb = (char*)d_ws;
    auto carve = [&](size_t bytes) -> void* {
        void* p = wsb + off; off += (bytes + 255) & ~(size_t)255; return p;
    };
    float* feat_t  = (float*)carve((size_t)BB * NN * CCH * HWF * 4);  // 68.8 MB
    float* acc     = (float*)carve(ACC_ELEMS * 4);                    // 20.5 MB
    uint2* entries = (uint2*)carve((size_t)MAXENT * 8);               //  8.6 MB
    int*   ebin    = (int*)  carve((size_t)MAXENT * 4);               //  4.3 MB
    float* conf    = (float*)carve((size_t)BB * NN * HWF * 4);        //  1.1 MB
    int*   counts  = (int*)  carve((NBINS_PAD + 256) * 4);
    int*   offsets = (int*)  carve((NBINS_PAD + 256) * 4);
    int*   cursor  = (int*)  carve((NBINS_PAD + 256) * 4);
    int*   bsum    = (int*)  carve(NSCANB * 4);
    int*   bbase   = (int*)  carve(NSCANB * 4);

    if (off <= ws_size) {
        hipMemsetAsync(counts, 0, (NBINS_PAD + 256) * 4, stream);
        hipMemsetAsync(acc, 0, ACC_ELEMS * 4, stream);

        dim3 pgrid((HWF + 255) / 256, BB * NN);        // (88,12)
        prep_kernel<<<pgrid, 256, 0, stream>>>(feat, depth, I_inv, E_inv, Vm,
                                               feat_t, conf, counts);

        scan1_kernel<<<NSCANB, 256, 0, stream>>>(counts, offsets, bsum);
        scan2_kernel<<<1, 64, 0, stream>>>(bsum, bbase);
        scan3_kernel<<<NSCANB, 256, 0, stream>>>(offsets, bbase, cursor);

        place_kernel<<<pgrid, 256, 0, stream>>>(conf, I_inv, E_inv, Vm,
                                                cursor, ebin, entries);

        gather_seg_kernel<<<NCHUNK / 4, 256, 0, stream>>>(
            ebin, entries, offsets + NBINS, feat_t, acc);

        dim3 fgrid(HWB / 64, BB);                      // (625,2)
        finalize_kernel<<<fgrid, 256, 0, stream>>>(acc, out);
    } else {
        float* acc0 = (float*)d_ws;
        hipMemsetAsync(acc0, 0, ACC_ELEMS * 4, stream);
        dim3 grid(HWF / 64, BB * NN);
        splat_kernel<<<grid, 256, 0, stream>>>(feat, depth, I_inv, E_inv, Vm, acc0);
        dim3 fgrid(HWB / 64, BB);
        finalize_kernel<<<fgrid, 256, 0, stream>>>(acc0, out);
    }
}

// Round 8
// 334.679 us; speedup vs baseline: 23.5751x; 1.0858x over previous
//
#include <hip/hip_runtime.h>

// LiftSplatBEV: B=2, N=6, C=64, HF=112, WF=200, D=64, BEV 200x200
#define BB   2
#define NN   6
#define CCH  64
#define HFE  112
#define WFE  200
#define DDE  64
#define HWF  (HFE*WFE)      // 22400 feature pixels (= 350*64); /4 = 5600 float4 groups
#define HWF4 (HWF/4)
#define BEVH 200
#define BEVW 200
#define HWB  (BEVH*BEVW)    // 40000 BEV cells
#define NBINS (BB*HWB)      // 80000 (b,cell) bins
#define NBINS_PAD 81920     // 320*256
#define NSCANB (NBINS_PAD/256)  // 320
#define MAXENT (BB*NN*HWF*4)    // 1,075,200 max entries (4 per valid slot)
#define NCHUNK (MAXENT/64)      // 16800 64-entry chunks
#define ACC_ELEMS ((size_t)BB*HWB*CCH)   // channel-last [b*HWB+cell][c]

__device__ __forceinline__ float4 f4max(float4 a, float4 b) {
    return make_float4(fmaxf(a.x,b.x), fmaxf(a.y,b.y), fmaxf(a.z,b.z), fmaxf(a.w,b.w));
}

// ---------------- shared geometry (bug-faithful to reference) ----------------
struct Geo {
    int valid;
    int c00, c10, c01, c11;
    float w00, w10, w01, w11;
};

__device__ __forceinline__ Geo geo_compute(int bn, int p,
    const float* __restrict__ I_inv, const float* __restrict__ E_inv,
    const float* __restrict__ Vm)
{
    Geo g; g.valid = 0;
    // bug-faithful w-outer flatten: u = p/112, v = p%112
    const float u = (float)(p / HFE);
    const float v = (float)(p % HFE);
    const float* Ii = I_inv + bn * 9;
    const float* Ei = E_inv + bn * 16;
    float cx = Ii[0]*u + Ii[1]*v + Ii[2];
    float cy = Ii[3]*u + Ii[4]*v + Ii[5];
    float cz = Ii[6]*u + Ii[7]*v + Ii[8];
    float tx = Ei[3], ty = Ei[7], tz = Ei[11];
    float dx = Ei[0]*cx + Ei[1]*cy + Ei[2] *cz + tx;   // includes translation (bug-faithful)
    float dy = Ei[4]*cx + Ei[5]*cy + Ei[6] *cz + ty;
    float dz = Ei[8]*cx + Ei[9]*cy + Ei[10]*cz + tz;
    float s  = -tz / fmaxf(dz, 1e-6f);
    float ex = tx + dx * s;
    float ey = ty + dy * s;
    float prx = Vm[0]*ex + Vm[1]*ey + Vm[2];
    float pry = Vm[3]*ex + Vm[4]*ey + Vm[5];
    float prz = Vm[6]*ex + Vm[7]*ey + Vm[8];
    float den = fmaxf(prz, 1e-7f);
    float bx = prx / den, by = pry / den;
    // bug-faithful gx->px roundtrip, same association order as reference
    float gx = bx / (float)(BEVW-1) * 2.0f - 1.0f;
    float gy = by / (float)(BEVH-1) * 2.0f - 1.0f;
    float px = (gx + 1.0f) * (float)(BEVW-1) / 2.0f;
    float py = (gy + 1.0f) * (float)(BEVH-1) / 2.0f;
    float x0f = fminf(fmaxf(floorf(px), 0.0f), (float)(BEVW-1));
    float y0f = fminf(fmaxf(floorf(py), 0.0f), (float)(BEVH-1));
    float x1f = fminf(x0f + 1.0f, (float)(BEVW-1));
    float y1f = fminf(y0f + 1.0f, (float)(BEVH-1));
    // far-edge-degenerate slots cancel exactly in the fp64 np reference: skip
    if (x0f == x1f || y0f == y1f) return g;
    float wx0 = x1f - px, wx1 = px - x0f;
    float wy0 = y1f - py, wy1 = py - y0f;
    int x0 = (int)x0f, x1 = (int)x1f, y0 = (int)y0f, y1 = (int)y1f;
    g.c00 = y0*BEVW + x0;  g.w00 = wx0*wy0;
    g.c10 = y0*BEVW + x1;  g.w10 = wx1*wy0;
    g.c01 = y1*BEVW + x0;  g.w01 = wx0*wy1;
    g.c11 = y1*BEVW + x1;  g.w11 = wx1*wy1;
    g.valid = 1;
    return g;
}

// Wave-run aggregation: consecutive lanes holding the same cell form a run.
__device__ __forceinline__ void run_info(int cell, int lane,
                                         bool& leader, int& runlen, int& leadlane)
{
    int prev = __shfl_up(cell, 1);
    bool change = (lane == 0) || (cell != prev);
    unsigned long long bal = __ballot(change);
    unsigned long long below = bal & (~0ull >> (63 - lane));
    leadlane = 63 - __builtin_clzll(below);
    unsigned long long above = (lane == 63) ? 0ull : (bal >> (lane + 1));
    int next = (above == 0ull) ? 64 : (lane + 1 + __builtin_ffsll((long long)above) - 1);
    runlen = next - lane;
    leader = change && (cell >= 0);
}

// ---------------- fused prep: conf(f4) + feat transpose(f4) + histogram ----------------
// Grid (88,12), block 256: p in [p0, p0+256) of camera bn.
__global__ __launch_bounds__(256) void prep_kernel(
    const float* __restrict__ feat,    // [12,64,22400]
    const float* __restrict__ depth,   // [12,64,22400]
    const float* __restrict__ I_inv, const float* __restrict__ E_inv,
    const float* __restrict__ Vm,
    float* __restrict__ feat_t,        // [12,22400,64]
    float* __restrict__ conf,          // [12,22400]
    int* __restrict__ counts)          // [NBINS_PAD]
{
    __shared__ float tile[2][64][66];  // stride 66 -> <=2-way bank alias (free, m136)
    __shared__ float4 cpart[4][64];

    const int bn   = blockIdx.y;
    const int p0   = blockIdx.x * 256;
    const int tid  = threadIdx.x, lane = tid & 63, wv = tid >> 6;
    const int c    = tid >> 2;         // 0..63 (transpose read channel / write pixel)
    const int q    = tid & 3;

    // -- conf partials: lane = float4 pixel-group, wave = 16-plane set. 16 indep f4 loads.
    const int gbase = blockIdx.x * 64;
    const bool gok  = (gbase + lane) < HWF4;
    float4 mx = make_float4(-1e30f, -1e30f, -1e30f, -1e30f);
    if (gok) {
        const float4* d4 = (const float4*)depth + (size_t)(bn * DDE + wv * 16) * HWF4 + gbase + lane;
        mx = d4[0];
#pragma unroll
        for (int d = 1; d < 16; ++d)
            mx = f4max(mx, d4[(size_t)d * HWF4]);
    }
    cpart[wv][lane] = mx;

    // -- transpose: 2 rounds x 2 tiles of 64 px (8 f4 loads in flight per round)
    const float* fcam = feat   + (size_t)bn * CCH * HWF;
    float*       ocam = feat_t + (size_t)bn * HWF * CCH;
#pragma unroll
    for (int r = 0; r < 2; ++r) {
        const int pb0 = p0 + 128 * r;
        if (pb0 < HWF) {
#pragma unroll
            for (int half = 0; half < 2; ++half) {
                const int pb = pb0 + 64 * half;
#pragma unroll
                for (int i = 0; i < 4; ++i) {
                    const int pg = q + 4 * i;           // 0..15
                    float4 f = *(const float4*)(fcam + (size_t)c * HWF + pb + 4 * pg);
                    tile[half][4*pg+0][c] = f.x;
                    tile[half][4*pg+1][c] = f.y;
                    tile[half][4*pg+2][c] = f.z;
                    tile[half][4*pg+3][c] = f.w;
                }
            }
        }
        __syncthreads();
        if (r == 0 && wv == 0 && gok) {
            // conf finalize by wave 0 (overlaps other waves' transpose writes)
            float4 mm = f4max(f4max(cpart[0][lane], cpart[1][lane]),
                              f4max(cpart[2][lane], cpart[3][lane]));
            *(float4*)(conf + (size_t)bn * HWF + 4 * (gbase + lane)) = mm;
        }
        if (pb0 < HWF) {
            const int px = c;                           // write pixel = tid>>2
#pragma unroll
            for (int half = 0; half < 2; ++half) {
                const int pb = pb0 + 64 * half;
#pragma unroll
                for (int i = 0; i < 4; ++i) {
                    const int cg = q + 4 * i;
                    float4 o;
                    o.x = tile[half][px][4*cg+0];
                    o.y = tile[half][px][4*cg+1];
                    o.z = tile[half][px][4*cg+2];
                    o.w = tile[half][px][4*cg+3];
                    *(float4*)(ocam + (size_t)(pb + px) * CCH + 4 * cg) = o;
                }
            }
        }
        __syncthreads();
    }

    // -- histogram with run-aggregated atomics
    const int p   = p0 + tid;
    const int inb = (p < HWF);
    Geo g = geo_compute(bn, inb ? p : HWF - 1, I_inv, E_inv, Vm);
    const int valid = inb && g.valid;
    const int base  = (bn / NN) * HWB;
    const int cells[4] = { valid ? base + g.c00 : -1, valid ? base + g.c10 : -1,
                           valid ? base + g.c01 : -1, valid ? base + g.c11 : -1 };
#pragma unroll
    for (int k = 0; k < 4; ++k) {
        bool leader; int runlen, leadlane;
        run_info(cells[k], lane, leader, runlen, leadlane);
        if (leader) atomicAdd(&counts[cells[k]], runlen);
    }
}

// D1: per-256-block exclusive scan of counts
__global__ __launch_bounds__(256) void scan1_kernel(
    const int* __restrict__ counts, int* __restrict__ offsets, int* __restrict__ bsum)
{
    __shared__ int tmp[256];
    const int t = threadIdx.x;
    const int i = blockIdx.x * 256 + t;
    int v = counts[i];
    tmp[t] = v; __syncthreads();
    for (int off = 1; off < 256; off <<= 1) {
        int x = (t >= off) ? tmp[t - off] : 0;
        __syncthreads();
        tmp[t] += x;
        __syncthreads();
    }
    offsets[i] = tmp[t] - v;
    if (t == 255) bsum[blockIdx.x] = tmp[255];
}

// D2+D3 merged: each block sums preceding block-sums itself, finalizes offsets+cursor.
__global__ __launch_bounds__(256) void scan3_kernel(
    int* __restrict__ offsets, const int* __restrict__ bsum, int* __restrict__ cursor)
{
    __shared__ int s[256];
    const int t = threadIdx.x;
    int part = 0;
    for (int i = t; i < blockIdx.x; i += 256) part += bsum[i];
    s[t] = part; __syncthreads();
    for (int off = 128; off > 0; off >>= 1) {
        if (t < off) s[t] += s[t + off];
        __syncthreads();
    }
    const int i = blockIdx.x * 256 + t;
    int v = offsets[i] + s[0];
    offsets[i] = v;
    cursor[i]  = v;
}

// E: place entries (lean), run-aggregated cursor atomics + contiguous run writes
__global__ __launch_bounds__(256) void place_kernel(
    const float* __restrict__ conf,
    const float* __restrict__ I_inv, const float* __restrict__ E_inv,
    const float* __restrict__ Vm,
    int* __restrict__ cursor, int* __restrict__ ebin, uint2* __restrict__ entries)
{
    const int bn = blockIdx.y;
    const int p  = blockIdx.x * blockDim.x + threadIdx.x;
    const int lane = threadIdx.x & 63;
    const int inb = (p < HWF);
    const int pp = inb ? p : HWF - 1;
    Geo g = geo_compute(bn, pp, I_inv, E_inv, Vm);
    const int valid = inb && g.valid;
    const int base = (bn / NN) * HWB;

    const float cf = conf[(size_t)bn * HWF + pp];
    const unsigned bnp = (unsigned)(bn * HWF + pp);
    const int   cells[4] = { valid ? base + g.c00 : -1, valid ? base + g.c10 : -1,
                             valid ? base + g.c01 : -1, valid ? base + g.c11 : -1 };
    const float ws[4] = { g.w00 * cf, g.w10 * cf, g.w01 * cf, g.w11 * cf };

#pragma unroll
    for (int k = 0; k < 4; ++k) {
        bool leader; int runlen, leadlane;
        run_info(cells[k], lane, leader, runlen, leadlane);
        int pos_leader = 0;
        if (leader) pos_leader = atomicAdd(&cursor[cells[k]], runlen);
        int pos = __shfl(pos_leader, leadlane) + (lane - leadlane);
        if (valid) {
            ebin[pos]    = cells[k];
            entries[pos] = make_uint2(bnp, __float_as_uint(ws[k]));
        }
    }
}

// F: segmented gather, one wave per 64-entry chunk, lane = channel, 8-deep MLP.
__global__ __launch_bounds__(256) void gather_seg_kernel(
    const int* __restrict__ ebin, const uint2* __restrict__ entries,
    const int* __restrict__ total_ptr,
    const float* __restrict__ feat_t, float* __restrict__ acc)
{
    const int lane = threadIdx.x & 63, wv = threadIdx.x >> 6;
    const int chunk = blockIdx.x * 4 + wv;
    const int total = *total_ptr;
    const int start = chunk * 64;
    if (start >= total) return;
    const int m = min(64, total - start);   // multiple of 4

    int myb = -1;
    uint2 mye = make_uint2(0u, 0u);
    if (lane < m) { myb = ebin[start + lane]; mye = entries[start + lane]; }

    float a = 0.0f;
    int j = 0;
    for (; j + 8 <= m; j += 8) {
        int bb[9]; unsigned xx[8], ww[8];
#pragma unroll
        for (int k = 0; k < 8; ++k) {
            bb[k] = __shfl(myb, j + k);
            xx[k] = (unsigned)__shfl((int)mye.x, j + k);
            ww[k] = (unsigned)__shfl((int)mye.y, j + k);
        }
        bb[8] = (j + 8 < 64) ? __shfl(myb, j + 8) : -2;
        float f[8];
#pragma unroll
        for (int k = 0; k < 8; ++k)
            f[k] = feat_t[(size_t)xx[k] * CCH + lane];   // 8 indep coalesced 256B loads
#pragma unroll
        for (int k = 0; k < 8; ++k) {
            a = fmaf(f[k], __uint_as_float(ww[k]), a);
            if (bb[k] != bb[k + 1]) { atomicAdd(&acc[(size_t)bb[k] * CCH + lane], a); a = 0.0f; }
        }
    }
    if (j < m) {   // 4-entry tail
        int bb[5]; unsigned xx[4], ww[4];
#pragma unroll
        for (int k = 0; k < 4; ++k) {
            bb[k] = __shfl(myb, j + k);
            xx[k] = (unsigned)__shfl((int)mye.x, j + k);
            ww[k] = (unsigned)__shfl((int)mye.y, j + k);
        }
        bb[4] = (j + 4 < 64) ? __shfl(myb, j + 4) : -2;
        float f[4];
#pragma unroll
        for (int k = 0; k < 4; ++k)
            f[k] = feat_t[(size_t)xx[k] * CCH + lane];
#pragma unroll
        for (int k = 0; k < 4; ++k) {
            a = fmaf(f[k], __uint_as_float(ww[k]), a);
            if (bb[k] != bb[k + 1]) { atomicAdd(&acc[(size_t)bb[k] * CCH + lane], a); a = 0.0f; }
        }
    }
}

// G: out[b][c][cell] = acc[b*HWB+cell][c] / 6 -- float4 both sides via LDS tile
__global__ __launch_bounds__(256) void finalize_kernel(
    const float* __restrict__ acc, float* __restrict__ out)
{
    __shared__ float t[64][66];
    const int b     = blockIdx.y;
    const int cell0 = blockIdx.x * 64;
    const int cc    = threadIdx.x >> 2;   // read: cell row / write: channel
    const int q     = threadIdx.x & 3;

    const float* abase = acc + ((size_t)b * HWB + cell0) * CCH;
#pragma unroll
    for (int i = 0; i < 4; ++i) {
        const int cg = q + 4 * i;
        float4 f = *(const float4*)(abase + (size_t)cc * CCH + 4 * cg);
        t[cc][4*cg+0] = f.x; t[cc][4*cg+1] = f.y;
        t[cc][4*cg+2] = f.z; t[cc][4*cg+3] = f.w;
    }
    __syncthreads();
    float* obase = out + (size_t)b * CCH * HWB + cell0;
#pragma unroll
    for (int i = 0; i < 4; ++i) {
        const int lg = q + 4 * i;           // cell-group
        float4 o;
        o.x = t[4*lg+0][cc] * (1.0f/6.0f);
        o.y = t[4*lg+1][cc] * (1.0f/6.0f);
        o.z = t[4*lg+2][cc] * (1.0f/6.0f);
        o.w = t[4*lg+3][cc] * (1.0f/6.0f);
        *(float4*)(obase + (size_t)cc * HWB + 4 * lg) = o;
    }
}

// ---------------- fallback (round-4 atomic splat) if ws too small ----------------
__global__ __launch_bounds__(256) void splat_kernel(
    const float* __restrict__ feat, const float* __restrict__ depth,
    const float* __restrict__ I_inv, const float* __restrict__ E_inv,
    const float* __restrict__ Vm, float* __restrict__ acc)
{
    __shared__ float fshare[64][65];
    __shared__ float cpart2[4][64];
    const int bn = blockIdx.y, b = bn / NN, p0 = blockIdx.x * 64;
    const int lane = threadIdx.x & 63, wv = threadIdx.x >> 6;
    const float* fbase = feat + (size_t)bn * CCH * HWF + p0;
#pragma unroll
    for (int c = wv; c < CCH; c += 4)
        fshare[lane][c] = fbase[(size_t)c * HWF + lane];
    const float* dbase = depth + (size_t)bn * DDE * HWF + p0;
    float m = dbase[(size_t)(wv * 16) * HWF + lane];
#pragma unroll
    for (int d = wv * 16 + 1; d < wv * 16 + 16; ++d)
        m = fmaxf(m, dbase[(size_t)d * HWF + lane]);
    cpart2[wv][lane] = m;
    __syncthreads();
    float* ab = acc + ((size_t)b * HWB) * CCH + lane;
    for (int s = wv * 16; s < wv * 16 + 16; ++s) {
        Geo g = geo_compute(bn, p0 + s, I_inv, E_inv, Vm);
        if (!g.valid) continue;
        float cf = fmaxf(fmaxf(cpart2[0][s], cpart2[1][s]), fmaxf(cpart2[2][s], cpart2[3][s]));
        float f = fshare[s][lane];
        atomicAdd(ab + (size_t)g.c00 * CCH, f * (g.w00 * cf));
        atomicAdd(ab + (size_t)g.c10 * CCH, f * (g.w10 * cf));
        atomicAdd(ab + (size_t)g.c01 * CCH, f * (g.w01 * cf));
        atomicAdd(ab + (size_t)g.c11 * CCH, f * (g.w11 * cf));
    }
}

extern "C" void kernel_launch(void* const* d_in, const int* in_sizes, int n_in,
                              void* d_out, int out_size, void* d_ws, size_t ws_size,
                              hipStream_t stream) {
    const float* feat  = (const float*)d_in[0];
    const float* depth = (const float*)d_in[1];
    const float* I_inv = (const float*)d_in[2];
    const float* E_inv = (const float*)d_in[3];
    const float* Vm    = (const float*)d_in[4];
    float* out = (float*)d_out;

    size_t off = 0;
    char* wsb = (char*)d_ws;
    auto carve = [&](size_t bytes) -> void* {
        void* p = wsb + off; off += (bytes + 255) & ~(size_t)255; return p;
    };
    // acc and counts adjacent -> single memset (acc bytes are 256B-multiple)
    float* feat_t  = (float*)carve((size_t)BB * NN * CCH * HWF * 4);  // 68.8 MB
    float* acc     = (float*)carve(ACC_ELEMS * 4);                    // 20.5 MB
    int*   counts  = (int*)  carve((NBINS_PAD + 256) * 4);            // 0.33 MB
    uint2* entries = (uint2*)carve((size_t)MAXENT * 8);               //  8.6 MB
    int*   ebin    = (int*)  carve((size_t)MAXENT * 4);               //  4.3 MB
    float* conf    = (float*)carve((size_t)BB * NN * HWF * 4);        //  1.1 MB
    int*   offsets = (int*)  carve((NBINS_PAD + 256) * 4);
    int*   cursor  = (int*)  carve((NBINS_PAD + 256) * 4);
    int*   bsum    = (int*)  carve(NSCANB * 4);

    if (off <= ws_size) {
        hipMemsetAsync(acc, 0, ACC_ELEMS * 4 + (NBINS_PAD + 256) * 4, stream);

        dim3 pgrid((HWF + 255) / 256, BB * NN);        // (88,12)
        prep_kernel<<<pgrid, 256, 0, stream>>>(feat, depth, I_inv, E_inv, Vm,
                                               feat_t, conf, counts);

        scan1_kernel<<<NSCANB, 256, 0, stream>>>(counts, offsets, bsum);
        scan3_kernel<<<NSCANB, 256, 0, stream>>>(offsets, bsum, cursor);

        place_kernel<<<pgrid, 256, 0, stream>>>(conf, I_inv, E_inv, Vm,
                                                cursor, ebin, entries);

        gather_seg_kernel<<<NCHUNK / 4, 256, 0, stream>>>(
            ebin, entries, offsets + NBINS, feat_t, acc);

        dim3 fgrid(HWB / 64, BB);                      // (625,2)
        finalize_kernel<<<fgrid, 256, 0, stream>>>(acc, out);
    } else {
        float* acc0 = (float*)d_ws;
        hipMemsetAsync(acc0, 0, ACC_ELEMS * 4, stream);
        dim3 grid(HWF / 64, BB * NN);
        splat_kernel<<<grid, 256, 0, stream>>>(feat, depth, I_inv, E_inv, Vm, acc0);
        dim3 fgrid(HWB / 64, BB);
        finalize_kernel<<<fgrid, 256, 0, stream>>>(acc0, out);
    }
}